// Round 5
// baseline (225.679 us; speedup 1.0000x reference)
//
#include <hip/hip_runtime.h>
#include <math.h>

#define TLEN 2048
#define T2   4096
#define H2   2048
#define NBLK 256          // fused kernel: 256 blocks x 2 channels each
#define EPS32 1.1920928955078125e-07
#define TOLV 5e-5

// ---- prep: coalesced transpose x:(B,T,C)->(c,t); twiddles; zero stats+barrier ----
__global__ void k_prep(const float* __restrict__ x, float* __restrict__ xr,
                       float2* __restrict__ tw, double* __restrict__ accs,
                       unsigned* __restrict__ bar){
  const int blk = blockIdx.x, tid = threadIdx.x;
  if (blk < 8){                       // 2048 twiddles e^{-i 2pi p/4096}, fp64-accurate
    int p = (blk << 8) + tid;
    double a = -6.283185307179586 * (double)p / 4096.0;
    tw[p] = make_float2((float)cos(a), (float)sin(a));
  }
  if (blk == 8){
    if (tid < 64) accs[tid] = 0.0;            // 4 slots x 16 doubles (128B padded)
    if (tid >= 64 && tid < 192) bar[tid - 64] = 0u;  // 4 x {counter,flag} padded
  }
  __shared__ float tile[64][65];
  const int b  = blk >> 5;
  const int t0 = (blk & 31) << 6;
  const int lo = tid & 63, r0 = tid >> 6;
  for (int pass = 0; pass < 16; ++pass){
    int tt = r0 + (pass << 2);
    tile[tt][lo] = x[((size_t)(b * TLEN + t0 + tt)) * 64 + lo];  // lo = ch, coalesced
  }
  __syncthreads();
  for (int pass = 0; pass < 16; ++pass){
    int c2 = r0 + (pass << 2);
    xr[((size_t)(b * 64 + c2)) * TLEN + t0 + lo] = tile[lo][c2]; // lo = t, coalesced
  }
}

// ---- 12-stage Stockham radix-2 FFT; result lands back in bufA ----
__device__ __forceinline__ void fft_stages(float2* bufA, float2* bufB,
                                           const float2* __restrict__ tw, float sgn){
  float2* src = bufA; float2* dst = bufB;
  const int tid = threadIdx.x;
  for (int st = 0; st < 12; ++st){
    int smask = (1 << st) - 1;
    #pragma unroll
    for (int pp = 0; pp < 8; ++pp){
      int idx = tid + (pp << 8);
      int p = idx >> st;
      int q = idx & smask;
      float2 a = src[idx];
      float2 b = src[idx + H2];
      float2 w = tw[p << st];
      float wy = sgn * w.y;
      float sx = a.x + b.x, sy = a.y + b.y;
      float dx = a.x - b.x, dy = a.y - b.y;
      dst[q + ((2 * p) << st)]     = make_float2(sx, sy);
      dst[q + ((2 * p + 1) << st)] = make_float2(dx * w.x - dy * wy, dx * wy + dy * w.x);
    }
    __syncthreads();
    float2* t = src; src = dst; dst = t;
  }
}

// ---- load mirror-extended signal into bufA ----
__device__ __forceinline__ void mirror_load(const float* __restrict__ f, float2* bufA){
  const int tid = threadIdx.x;
  #pragma unroll
  for (int pp = 0; pp < 16; ++pp){
    int i = tid + (pp << 8);
    int s = (i < 1024) ? (1023 - i) : ((i < 3072) ? (i - 1024) : (5119 - i));
    bufA[i] = make_float2(f[s], 0.0f);
  }
}

// ---- fused VMD: 2 FFTs + 5 iterations (u,F in VGPRs, grid barriers) + 2 IFFTs ----
// 256 blocks x 256 thr x 64KB LDS: worst-case 2 blocks/CU always fits (128<=160KB),
// so all 256 blocks are unconditionally co-resident on 256 CUs -> spin barrier safe.
__launch_bounds__(256, 1)
__global__ void k_vmd(const float* __restrict__ xr, const float2* __restrict__ tw,
                      double* __restrict__ accs, unsigned* __restrict__ bar,
                      float* __restrict__ xl_s){
  __shared__ float2 bufA[T2];
  __shared__ float2 bufB[T2];
  __shared__ double red[40];
  const int tid = threadIdx.x;
  const int wave = tid >> 6, lane = tid & 63;
  const int c0 = blockIdx.x * 2, c1 = c0 + 1;

  // ---- forward FFTs, spectra kept in registers ----
  float2 F0[8], F1[8];
  mirror_load(xr + (size_t)c0 * TLEN, bufA);
  __syncthreads();
  fft_stages(bufA, bufB, tw, 1.0f);
  #pragma unroll
  for (int pp = 0; pp < 8; ++pp) F0[pp] = bufA[tid + (pp << 8)];
  __syncthreads();
  mirror_load(xr + (size_t)c1 * TLEN, bufA);
  __syncthreads();
  fft_stages(bufA, bufB, tw, 1.0f);
  #pragma unroll
  for (int pp = 0; pp < 8; ++pp) F1[pp] = bufA[tid + (pp << 8)];

  // ---- VMD state in registers: u[ch][mode][pp] ----
  float2 u[2][4][8];
  #pragma unroll
  for (int s = 0; s < 2; ++s)
    #pragma unroll
    for (int k = 0; k < 4; ++k)
      #pragma unroll
      for (int pp = 0; pp < 8; ++pp) u[s][k][pp] = make_float2(0.f, 0.f);

  float om[4] = {0.0f, 0.125f, 0.25f, 0.375f};
  bool active = true;

  for (int it = 0; it < 4; ++it){         // reference iterations 1..4 (with stats)
    if (active){
      double aFP[4] = {0,0,0,0}, aP[4] = {0,0,0,0}, aD = 0.0;
      #pragma unroll
      for (int s = 0; s < 2; ++s){
        #pragma unroll
        for (int pp = 0; pp < 8; ++pp){
          int j = tid + (pp << 8);
          float fj = (float)j * (1.0f / 4096.0f);
          float Fx = s ? F1[pp].x : F0[pp].x;
          float Fy = s ? F1[pp].y : F0[pp].y;
          float sx = u[s][0][pp].x + u[s][1][pp].x + u[s][2][pp].x + u[s][3][pp].x;
          float sy = u[s][0][pp].y + u[s][1][pp].y + u[s][2][pp].y + u[s][3][pp].y;
          #pragma unroll
          for (int k = 0; k < 4; ++k){
            float ox = sx - u[s][k][pp].x, oy = sy - u[s][k][pp].y;
            float d = fj - om[k];
            float den = 1.0f + 2000.0f * d * d;
            float nx = (Fx - ox) / den, ny = (Fy - oy) / den;
            float pw = nx * nx + ny * ny;
            aFP[k] += (double)(fj * pw);
            aP[k]  += (double)pw;
            float ddx = nx - u[s][k][pp].x, ddy = ny - u[s][k][pp].y;
            aD += (double)(ddx * ddx + ddy * ddy);
            u[s][k][pp] = make_float2(nx, ny);
            sx = ox + nx; sy = oy + ny;
          }
        }
      }
      // block-reduce 9 doubles -> atomicAdd into this iteration's padded slot
      double acc9[9] = {aFP[0],aFP[1],aFP[2],aFP[3],aP[0],aP[1],aP[2],aP[3],aD};
      #pragma unroll
      for (int i = 0; i < 9; ++i){
        double v = acc9[i];
        for (int off = 32; off; off >>= 1) v += __shfl_down(v, off);
        if (lane == 0) red[i * 4 + wave] = v;
      }
      __syncthreads();
      if (tid < 9)
        atomicAdd(&accs[it * 16 + tid],
                  red[tid*4+0] + red[tid*4+1] + red[tid*4+2] + red[tid*4+3]);
    }
    // ---- grid barrier (always; `active` is grid-uniform) ----
    if (tid == 0){
      __threadfence();
      unsigned* cnt  = bar + it * 32;
      unsigned* flag = bar + it * 32 + 16;
      unsigned old = __hip_atomic_fetch_add(cnt, 1u, __ATOMIC_ACQ_REL,
                                            __HIP_MEMORY_SCOPE_AGENT);
      if (old == NBLK - 1u){
        __hip_atomic_store(flag, 1u, __ATOMIC_RELEASE, __HIP_MEMORY_SCOPE_AGENT);
      } else {
        while (__hip_atomic_load(flag, __ATOMIC_ACQUIRE,
                                 __HIP_MEMORY_SCOPE_AGENT) == 0u)
          __builtin_amdgcn_s_sleep(8);
      }
    }
    __syncthreads();
    if (active){
      if (tid == 0){
        #pragma unroll
        for (int i = 0; i < 9; ++i)
          red[i] = __hip_atomic_load(&accs[it * 16 + i], __ATOMIC_RELAXED,
                                     __HIP_MEMORY_SCOPE_AGENT);
      }
      __syncthreads();
      #pragma unroll
      for (int k = 0; k < 4; ++k) om[k] = (float)(red[k] / red[4 + k]);
      double ud = red[8] * (1.0 / 4096.0) + EPS32;
      active = (ud > TOLV);
    }
    __syncthreads();   // red safe to reuse next iteration
  }

  // ---- reference iteration 5: only mode-0 matters downstream ----
  if (active){
    #pragma unroll
    for (int s = 0; s < 2; ++s){
      #pragma unroll
      for (int pp = 0; pp < 8; ++pp){
        int j = tid + (pp << 8);
        float fj = (float)j * (1.0f / 4096.0f);
        float Fx = s ? F1[pp].x : F0[pp].x;
        float Fy = s ? F1[pp].y : F0[pp].y;
        float ox = u[s][1][pp].x + u[s][2][pp].x + u[s][3][pp].x;
        float oy = u[s][1][pp].y + u[s][2][pp].y + u[s][3][pp].y;
        float d = fj - om[0];
        float den = 1.0f + 2000.0f * d * d;
        u[s][0][pp] = make_float2((Fx - ox) / den, (Fy - oy) / den);
      }
    }
  }

  // ---- Hermitian build (reference quirks) + inverse FFT, per channel ----
  const float scale = 1.0f / (float)T2;
  #pragma unroll
  for (int s = 0; s < 2; ++s){
    __syncthreads();
    #pragma unroll
    for (int pp = 0; pp < 8; ++pp){
      int j = tid + (pp << 8);
      float2 v = u[s][0][pp];
      if (j == 0){
        bufA[0] = make_float2(v.x, -v.y);            // S[0] = conj(U[0])
      } else {
        bufA[j]      = v;                            // S[j] = U[j]
        bufA[T2 - j] = make_float2(v.x, -v.y);       // S[4096-j] = conj(U[j])
      }
      if (j == H2 - 1) bufA[H2] = make_float2(v.x, -v.y);  // S[2048] = conj(U[2047])
    }
    __syncthreads();
    fft_stages(bufA, bufB, tw, -1.0f);
    float* out = xl_s + (size_t)(s ? c1 : c0) * TLEN;
    #pragma unroll
    for (int pp = 0; pp < 8; ++pp){
      int t = tid + (pp << 8);
      out[t] = bufA[1024 + t].x * scale;
    }
  }
}

// ---- transpose back + x_h = x - x_l ----
__global__ void k_tout(const float* __restrict__ x, const float* __restrict__ xl_s,
                       float* __restrict__ xh, float* __restrict__ xl){
  __shared__ float tile[64][65];
  int blk = blockIdx.x;
  int b  = blk >> 5;
  int t0 = (blk & 31) << 6;
  int lo = threadIdx.x & 63;
  int r0 = threadIdx.x >> 6;
  for (int pass = 0; pass < 16; ++pass){
    int c2 = r0 + (pass << 2);
    tile[c2][lo] = xl_s[((size_t)(b * 64 + c2)) * TLEN + t0 + lo];
  }
  __syncthreads();
  for (int pass = 0; pass < 16; ++pass){
    int tt = r0 + (pass << 2);
    size_t oi = ((size_t)(b * TLEN + t0 + tt)) * 64 + lo;
    float xlv = tile[lo][tt];
    float xv  = x[oi];
    xh[oi] = xv - xlv;
    xl[oi] = xlv;
  }
}

extern "C" void kernel_launch(void* const* d_in, const int* in_sizes, int n_in,
                              void* d_out, int out_size, void* d_ws, size_t ws_size,
                              hipStream_t stream){
  const float* x = (const float*)d_in[0];
  float* out_xh = (float*)d_out;
  float* out_xl = out_xh + (size_t)8 * TLEN * 64;

  char* ws = (char*)d_ws;
  float*    xr   = (float*)ws;                               // 4 MiB
  float*    xl_s = (float*)(ws + ((size_t)4 << 20));         // 4 MiB
  float2*   tw   = (float2*)(ws + ((size_t)8 << 20));        // 16 KiB
  double*   accs = (double*)(ws + ((size_t)8 << 20) + 16384);   // 64 doubles (padded)
  unsigned* bar  = (unsigned*)(ws + ((size_t)8 << 20) + 16384 + 512); // 128 uints

  k_prep<<<256, 256, 0, stream>>>(x, xr, tw, accs, bar);
  k_vmd<<<NBLK, 256, 0, stream>>>(xr, tw, accs, bar, xl_s);
  k_tout<<<256, 256, 0, stream>>>(x, xl_s, out_xh, out_xl);
}

// Round 6
// 208.819 us; speedup vs baseline: 1.0807x; 1.0807x over previous
//
#include <hip/hip_runtime.h>
#include <math.h>

#define TLEN 2048
#define T2   4096
#define H2   2048
#define NBLK 256          // fused kernel: 256 blocks x 2 channels each = 1 block/CU
#define EPS32 1.1920928955078125e-07
#define TOLV 5e-5
// bijective LDS swizzle: makes stride-16 writes and stride-256 reads conflict-free
#define PHI(i) ((i) ^ (((i) >> 4) & 15))

__device__ __forceinline__ float2 cmulf(float2 a, float2 b){
  return make_float2(a.x * b.x - a.y * b.y, a.x * b.y + a.y * b.x);
}

// radix-4 butterfly in regs; s=+1 forward (W4=-i), s=-1 inverse (W4=+i)
__device__ __forceinline__ void dft4(float2& x0, float2& x1, float2& x2, float2& x3, float s){
  float t0x = x0.x + x2.x, t0y = x0.y + x2.y;
  float t1x = x0.x - x2.x, t1y = x0.y - x2.y;
  float t2x = x1.x + x3.x, t2y = x1.y + x3.y;
  float t3x = x1.x - x3.x, t3y = x1.y - x3.y;
  float r3x = s * t3y, r3y = -s * t3x;        // (-i*s) * t3
  x0 = make_float2(t0x + t2x, t0y + t2y);
  x1 = make_float2(t1x + r3x, t1y + r3y);
  x2 = make_float2(t0x - t2x, t0y - t2y);
  x3 = make_float2(t1x - r3x, t1y - r3y);
}

// 16-point FFT in registers: DFT4 over m1, W16^(u0*m0) twiddles, DFT4 over m0.
// Input v[m]=x[m] natural; output X[u0+4*u1] lands in v[4*u0+u1].
__device__ __forceinline__ void fft16r(float2* v, float s){
  const float C[10] = {1.f, 0.92387953251128674f, 0.70710678118654752f, 0.38268343236508977f,
                       0.f, 0.f, -0.70710678118654752f, 0.f, 0.f, -0.92387953251128674f};
  const float S[10] = {0.f, -0.38268343236508977f, -0.70710678118654752f, -0.92387953251128674f,
                       -1.f, 0.f, -0.70710678118654752f, 0.f, 0.f, 0.38268343236508977f};
  #pragma unroll
  for (int m0 = 0; m0 < 4; ++m0) dft4(v[m0], v[4 + m0], v[8 + m0], v[12 + m0], s);
  #pragma unroll
  for (int u0 = 1; u0 < 4; ++u0)
    #pragma unroll
    for (int m0 = 1; m0 < 4; ++m0){
      int k = u0 * m0;
      v[(u0 << 2) + m0] = cmulf(v[(u0 << 2) + m0], make_float2(C[k], s * S[k]));
    }
  #pragma unroll
  for (int u0 = 0; u0 < 4; ++u0)
    dft4(v[u0 << 2], v[(u0 << 2) + 1], v[(u0 << 2) + 2], v[(u0 << 2) + 3], s);
}

// 4096-pt FFT: 3 radix-16 Stockham stages. Input in bufA (PHI layout), result in
// bufB (PHI layout, natural bin order). s=+1: e^{-i..} fwd; s=-1: e^{+i..} inv.
// Trailing __syncthreads included.
__device__ __forceinline__ void fft4096(float2* bufA, float2* bufB,
                                        const float2* __restrict__ tw, float s){
  const int tid = threadIdx.x;
  float2 v[16];
  // ---- stage 0: L=1, p=tid; twiddle W4096^{u*p} ----
  #pragma unroll
  for (int m = 0; m < 16; ++m) v[m] = bufA[PHI(tid + (m << 8))];
  fft16r(v, s);
  #pragma unroll
  for (int u0 = 0; u0 < 4; ++u0)
    #pragma unroll
    for (int u1 = 0; u1 < 4; ++u1){
      int u = u0 + (u1 << 2);
      float2 X = v[(u0 << 2) + u1];
      if (u){ float2 w = tw[u * tid]; X = cmulf(X, make_float2(w.x, s * w.y)); }
      bufB[PHI((tid << 4) + u)] = X;
    }
  __syncthreads();
  // ---- stage 1: L=16, p=tid>>4, q=tid&15; twiddle W4096^{u*p*16} ----
  #pragma unroll
  for (int m = 0; m < 16; ++m) v[m] = bufB[PHI(tid + (m << 8))];
  fft16r(v, s);
  {
    const int p = tid >> 4, q = tid & 15;
    #pragma unroll
    for (int u0 = 0; u0 < 4; ++u0)
      #pragma unroll
      for (int u1 = 0; u1 < 4; ++u1){
        int u = u0 + (u1 << 2);
        float2 X = v[(u0 << 2) + u1];
        if (u){ float2 w = tw[(u * p) << 4]; X = cmulf(X, make_float2(w.x, s * w.y)); }
        bufA[PHI(q + (((p << 4) + u) << 4))] = X;
      }
  }
  __syncthreads();
  // ---- stage 2: L=256, p=0, q=tid; no twiddle ----
  #pragma unroll
  for (int m = 0; m < 16; ++m) v[m] = bufA[PHI(tid + (m << 8))];
  fft16r(v, s);
  #pragma unroll
  for (int u0 = 0; u0 < 4; ++u0)
    #pragma unroll
    for (int u1 = 0; u1 < 4; ++u1){
      int u = u0 + (u1 << 2);
      bufB[PHI(tid + (u << 8))] = v[(u0 << 2) + u1];
    }
  __syncthreads();
}

// ---- prep: coalesced transpose x:(B,T,C)->(c,t); 4096 twiddles; zero stats/bar ----
__global__ void k_prep(const float* __restrict__ x, float* __restrict__ xr,
                       float2* __restrict__ tw, double* __restrict__ accs,
                       unsigned* __restrict__ bar){
  const int blk = blockIdx.x, tid = threadIdx.x;
  if (blk < 16){                      // 4096 twiddles e^{-i 2pi p/4096}, fp64-accurate
    int p = (blk << 8) + tid;
    double a = -6.283185307179586 * (double)p / 4096.0;
    tw[p] = make_float2((float)cos(a), (float)sin(a));
  }
  if (blk == 16){
    if (tid < 64) accs[tid] = 0.0;
    if (tid >= 64 && tid < 192) bar[tid - 64] = 0u;
  }
  __shared__ float tile[64][65];
  const int b  = blk >> 5;
  const int t0 = (blk & 31) << 6;
  const int lo = tid & 63, r0 = tid >> 6;
  for (int pass = 0; pass < 16; ++pass){
    int tt = r0 + (pass << 2);
    tile[tt][lo] = x[((size_t)(b * TLEN + t0 + tt)) * 64 + lo];
  }
  __syncthreads();
  for (int pass = 0; pass < 16; ++pass){
    int c2 = r0 + (pass << 2);
    xr[((size_t)(b * 64 + c2)) * TLEN + t0 + lo] = tile[lo][c2];
  }
}

// ---- load mirror-extended signal into bufA (PHI layout) ----
__device__ __forceinline__ void mirror_load(const float* __restrict__ f, float2* bufA){
  const int tid = threadIdx.x;
  #pragma unroll
  for (int pp = 0; pp < 16; ++pp){
    int i = tid + (pp << 8);
    int s = (i < 1024) ? (1023 - i) : ((i < 3072) ? (i - 1024) : (5119 - i));
    bufA[PHI(i)] = make_float2(f[s], 0.0f);
  }
}

// ---- fused VMD: 2 fwd FFTs + 5 iterations (u,F in VGPRs, grid barriers) + 2 IFFTs ----
__launch_bounds__(256, 1)
__global__ void k_vmd(const float* __restrict__ xr, const float2* __restrict__ tw,
                      double* __restrict__ accs, unsigned* __restrict__ bar,
                      float* __restrict__ xl_s){
  __shared__ float2 bufA[T2];
  __shared__ float2 bufB[T2];
  __shared__ double red[40];
  const int tid = threadIdx.x;
  const int wave = tid >> 6, lane = tid & 63;
  const int c0 = blockIdx.x * 2, c1 = c0 + 1;

  float2 F0[8], F1[8];
  mirror_load(xr + (size_t)c0 * TLEN, bufA);
  __syncthreads();
  fft4096(bufA, bufB, tw, 1.0f);
  #pragma unroll
  for (int pp = 0; pp < 8; ++pp) F0[pp] = bufB[PHI(tid + (pp << 8))];
  __syncthreads();
  mirror_load(xr + (size_t)c1 * TLEN, bufA);
  __syncthreads();
  fft4096(bufA, bufB, tw, 1.0f);
  #pragma unroll
  for (int pp = 0; pp < 8; ++pp) F1[pp] = bufB[PHI(tid + (pp << 8))];

  // ---- VMD state in registers ----
  float2 u[2][4][8];
  #pragma unroll
  for (int s = 0; s < 2; ++s)
    #pragma unroll
    for (int k = 0; k < 4; ++k)
      #pragma unroll
      for (int pp = 0; pp < 8; ++pp) u[s][k][pp] = make_float2(0.f, 0.f);

  float om[4] = {0.0f, 0.125f, 0.25f, 0.375f};
  bool active = true;

  for (int it = 0; it < 4; ++it){         // reference iterations 1..4 (with stats)
    if (active){
      double aFP[4] = {0,0,0,0}, aP[4] = {0,0,0,0}, aD = 0.0;
      #pragma unroll
      for (int s = 0; s < 2; ++s){
        #pragma unroll
        for (int pp = 0; pp < 8; ++pp){
          int j = tid + (pp << 8);
          float fj = (float)j * (1.0f / 4096.0f);
          float Fx = s ? F1[pp].x : F0[pp].x;
          float Fy = s ? F1[pp].y : F0[pp].y;
          float sx = u[s][0][pp].x + u[s][1][pp].x + u[s][2][pp].x + u[s][3][pp].x;
          float sy = u[s][0][pp].y + u[s][1][pp].y + u[s][2][pp].y + u[s][3][pp].y;
          #pragma unroll
          for (int k = 0; k < 4; ++k){
            float ox = sx - u[s][k][pp].x, oy = sy - u[s][k][pp].y;
            float d = fj - om[k];
            float den = 1.0f + 2000.0f * d * d;
            float nx = (Fx - ox) / den, ny = (Fy - oy) / den;
            float pw = nx * nx + ny * ny;
            aFP[k] += (double)(fj * pw);
            aP[k]  += (double)pw;
            float ddx = nx - u[s][k][pp].x, ddy = ny - u[s][k][pp].y;
            aD += (double)(ddx * ddx + ddy * ddy);
            u[s][k][pp] = make_float2(nx, ny);
            sx = ox + nx; sy = oy + ny;
          }
        }
      }
      double acc9[9] = {aFP[0],aFP[1],aFP[2],aFP[3],aP[0],aP[1],aP[2],aP[3],aD};
      #pragma unroll
      for (int i = 0; i < 9; ++i){
        double v = acc9[i];
        for (int off = 32; off; off >>= 1) v += __shfl_down(v, off);
        if (lane == 0) red[i * 4 + wave] = v;
      }
      __syncthreads();
      if (tid < 9)
        atomicAdd(&accs[it * 16 + tid],
                  red[tid*4+0] + red[tid*4+1] + red[tid*4+2] + red[tid*4+3]);
    }
    // ---- grid barrier (always; `active` is grid-uniform) ----
    if (tid == 0){
      __threadfence();
      unsigned* cnt  = bar + it * 32;
      unsigned* flag = bar + it * 32 + 16;
      unsigned old = __hip_atomic_fetch_add(cnt, 1u, __ATOMIC_ACQ_REL,
                                            __HIP_MEMORY_SCOPE_AGENT);
      if (old == NBLK - 1u){
        __hip_atomic_store(flag, 1u, __ATOMIC_RELEASE, __HIP_MEMORY_SCOPE_AGENT);
      } else {
        while (__hip_atomic_load(flag, __ATOMIC_ACQUIRE,
                                 __HIP_MEMORY_SCOPE_AGENT) == 0u)
          __builtin_amdgcn_s_sleep(8);
      }
    }
    __syncthreads();
    if (active){
      if (tid == 0){
        #pragma unroll
        for (int i = 0; i < 9; ++i)
          red[i] = __hip_atomic_load(&accs[it * 16 + i], __ATOMIC_RELAXED,
                                     __HIP_MEMORY_SCOPE_AGENT);
      }
      __syncthreads();
      #pragma unroll
      for (int k = 0; k < 4; ++k) om[k] = (float)(red[k] / red[4 + k]);
      double ud = red[8] * (1.0 / 4096.0) + EPS32;
      active = (ud > TOLV);
    }
    __syncthreads();
  }

  // ---- reference iteration 5: only mode-0 matters downstream ----
  if (active){
    #pragma unroll
    for (int s = 0; s < 2; ++s){
      #pragma unroll
      for (int pp = 0; pp < 8; ++pp){
        int j = tid + (pp << 8);
        float fj = (float)j * (1.0f / 4096.0f);
        float Fx = s ? F1[pp].x : F0[pp].x;
        float Fy = s ? F1[pp].y : F0[pp].y;
        float ox = u[s][1][pp].x + u[s][2][pp].x + u[s][3][pp].x;
        float oy = u[s][1][pp].y + u[s][2][pp].y + u[s][3][pp].y;
        float d = fj - om[0];
        float den = 1.0f + 2000.0f * d * d;
        u[s][0][pp] = make_float2((Fx - ox) / den, (Fy - oy) / den);
      }
    }
  }

  // ---- Hermitian build (reference quirks) + inverse FFT, per channel ----
  const float scale = 1.0f / (float)T2;
  #pragma unroll
  for (int s = 0; s < 2; ++s){
    __syncthreads();
    #pragma unroll
    for (int pp = 0; pp < 8; ++pp){
      int j = tid + (pp << 8);
      float2 v = u[s][0][pp];
      if (j == 0){
        bufA[PHI(0)] = make_float2(v.x, -v.y);          // S[0] = conj(U[0])
      } else {
        bufA[PHI(j)]      = v;                          // S[j] = U[j]
        bufA[PHI(T2 - j)] = make_float2(v.x, -v.y);     // S[4096-j] = conj(U[j])
      }
      if (j == H2 - 1) bufA[PHI(H2)] = make_float2(v.x, -v.y); // S[2048]=conj(U[2047])
    }
    __syncthreads();
    fft4096(bufA, bufB, tw, -1.0f);
    float* out = xl_s + (size_t)(s ? c1 : c0) * TLEN;
    #pragma unroll
    for (int pp = 0; pp < 8; ++pp){
      int t = tid + (pp << 8);
      out[t] = bufB[PHI(1024 + t)].x * scale;
    }
  }
}

// ---- transpose back + x_h = x - x_l ----
__global__ void k_tout(const float* __restrict__ x, const float* __restrict__ xl_s,
                       float* __restrict__ xh, float* __restrict__ xl){
  __shared__ float tile[64][65];
  int blk = blockIdx.x;
  int b  = blk >> 5;
  int t0 = (blk & 31) << 6;
  int lo = threadIdx.x & 63;
  int r0 = threadIdx.x >> 6;
  for (int pass = 0; pass < 16; ++pass){
    int c2 = r0 + (pass << 2);
    tile[c2][lo] = xl_s[((size_t)(b * 64 + c2)) * TLEN + t0 + lo];
  }
  __syncthreads();
  for (int pass = 0; pass < 16; ++pass){
    int tt = r0 + (pass << 2);
    size_t oi = ((size_t)(b * TLEN + t0 + tt)) * 64 + lo;
    float xlv = tile[lo][tt];
    float xv  = x[oi];
    xh[oi] = xv - xlv;
    xl[oi] = xlv;
  }
}

extern "C" void kernel_launch(void* const* d_in, const int* in_sizes, int n_in,
                              void* d_out, int out_size, void* d_ws, size_t ws_size,
                              hipStream_t stream){
  const float* x = (const float*)d_in[0];
  float* out_xh = (float*)d_out;
  float* out_xl = out_xh + (size_t)8 * TLEN * 64;

  char* ws = (char*)d_ws;
  float*    xr   = (float*)ws;                               // 4 MiB
  float*    xl_s = (float*)(ws + ((size_t)4 << 20));         // 4 MiB
  float2*   tw   = (float2*)(ws + ((size_t)8 << 20));        // 32 KiB (4096 entries)
  double*   accs = (double*)(ws + ((size_t)8 << 20) + 32768);    // 64 doubles (padded)
  unsigned* bar  = (unsigned*)(ws + ((size_t)8 << 20) + 32768 + 512); // 128 uints

  k_prep<<<256, 256, 0, stream>>>(x, xr, tw, accs, bar);
  k_vmd<<<NBLK, 256, 0, stream>>>(xr, tw, accs, bar, xl_s);
  k_tout<<<256, 256, 0, stream>>>(x, xl_s, out_xh, out_xl);
}